// Round 3
// baseline (444.913 us; speedup 1.0000x reference)
//
#include <hip/hip_runtime.h>
#include <hip/hip_bf16.h>

// SimpleVectorQuantizer: vecs [16,32,128,64] f32, codebook [512,64] f32.
// Outputs (flat f32, concatenated): vecs_hat [65536*64], z [65536] (as float),
// l_commit [1], l_codebook [1].
//
// Round 3: replicate the np reference's f32 ROUNDING, not out-precise it.
// Evidence: f32 (r1) and f64 (r2) kernels gave bit-identical z mismatches
// (absmax 355) -> both compute the TRUE argmin; the reference computes
// argmin over f32-quantized scores  fl32(fl32(vsq - 2e) + csq)  at magnitude
// ~64 (ulp 7.6e-6), which ties/flips ~5-10 of 65536 vectors vs truth.
// So: e = exact f64 dot rounded to f32 (within ref's own einsum error),
// then the ref's exact outer f32 arithmetic, then first-index argmin.

#define VQ_K 64
#define VQ_S 512
#define BLOCK 256

// Precompute f64 codebook copy + csq32[s] = (float)sum_k c^2 (exact f64 sum).
__global__ void vq_prep(const float* __restrict__ cb,
                        double* __restrict__ cb64,
                        float* __restrict__ csq32) {
    int s = blockIdx.x * 64 + threadIdx.x;   // 8 blocks x 64 threads
    if (s >= VQ_S) return;
    const float* row = cb + (size_t)s * VQ_K;
    double* orow = cb64 + (size_t)s * VQ_K;
    double acc = 0.0;
#pragma unroll
    for (int k = 0; k < VQ_K; ++k) {
        double c = (double)row[k];
        orow[k] = c;
        acc = fma(c, c, acc);
    }
    csq32[s] = (float)acc;
}

__global__ __launch_bounds__(BLOCK) void vq_main(
    const float* __restrict__ vecs,
    const float* __restrict__ codebook,
    const double* __restrict__ cb64,
    const float* __restrict__ csq32,
    float* __restrict__ out_hat,
    float* __restrict__ out_z,
    float* __restrict__ out_loss,   // 2 floats, pre-zeroed
    double inv_n) {
    const int vec = blockIdx.x * BLOCK + threadIdx.x;

    // Load this thread's vector; keep f64 copy for exact dots.
    double v[VQ_K];
    {
        const float4* vp = (const float4*)(vecs + (size_t)vec * VQ_K);
#pragma unroll
        for (int i = 0; i < VQ_K / 4; ++i) {
            float4 t = vp[i];
            v[4 * i + 0] = (double)t.x;
            v[4 * i + 1] = (double)t.y;
            v[4 * i + 2] = (double)t.z;
            v[4 * i + 3] = (double)t.w;
        }
    }
    double vsq64 = 0.0;
#pragma unroll
    for (int k = 0; k < VQ_K; ++k) vsq64 = fma(v[k], v[k], vsq64);
    const float vsq = (float)vsq64;

    // Scan codewords. e_s = exact f64 dot -> f32; then the reference's
    // outer f32 arithmetic:  score = fl32(fl32(vsq - 2*e) + csq).
    // (2*e is exact in f32, so contraction cannot alter the rounding.)
    float best = 3.4e38f;
    int bidx = 0;
    for (int s = 0; s < VQ_S; s += 4) {
        const double* crow = cb64 + (size_t)s * VQ_K;  // wave-uniform
        double a0 = 0.0, a1 = 0.0, a2 = 0.0, a3 = 0.0;
#pragma unroll
        for (int k = 0; k < VQ_K; ++k) {
            double vk = v[k];
            a0 = fma(crow[k + 0 * VQ_K], vk, a0);
            a1 = fma(crow[k + 1 * VQ_K], vk, a1);
            a2 = fma(crow[k + 2 * VQ_K], vk, a2);
            a3 = fma(crow[k + 3 * VQ_K], vk, a3);
        }
        float e0 = (float)a0, e1 = (float)a1, e2 = (float)a2, e3 = (float)a3;
        float s0 = (vsq - 2.0f * e0) + csq32[s + 0];
        float s1 = (vsq - 2.0f * e1) + csq32[s + 1];
        float s2 = (vsq - 2.0f * e2) + csq32[s + 2];
        float s3 = (vsq - 2.0f * e3) + csq32[s + 3];
        // Sequential strict-< keeps the FIRST minimal index (np.argmin).
        if (s0 < best) { best = s0; bidx = s + 0; }
        if (s1 < best) { best = s1; bidx = s + 1; }
        if (s2 < best) { best = s2; bidx = s + 2; }
        if (s3 < best) { best = s3; bidx = s + 3; }
    }

    // Loss: relu(min score) / n, into both loss slots.
    double d = (double)(best < 0.0f ? 0.0f : best);
    d *= inv_n;
#pragma unroll
    for (int off = 32; off >= 1; off >>= 1) d += __shfl_down(d, off, 64);
    if ((threadIdx.x & 63) == 0) {
        float df = (float)d;
        atomicAdd(&out_loss[0], df);
        atomicAdd(&out_loss[1], df);
    }

    // z as float (flat f32 output buffer).
    out_z[vec] = (float)bidx;

    // Cooperative coalesced gather/store of vecs_hat for this block.
    __shared__ int zsh[BLOCK];
    zsh[threadIdx.x] = bidx;
    __syncthreads();
    const float4* cb4 = (const float4*)codebook;
    float4* hat4 = (float4*)(out_hat + (size_t)blockIdx.x * BLOCK * VQ_K);
    const int F = BLOCK * (VQ_K / 4);
#pragma unroll
    for (int f = threadIdx.x; f < F; f += BLOCK) {
        int vloc = f >> 4;       // local vector
        int k4 = f & 15;         // float4 within it
        hat4[f] = cb4[zsh[vloc] * (VQ_K / 4) + k4];
    }
}

extern "C" void kernel_launch(void* const* d_in, const int* in_sizes, int n_in,
                              void* d_out, int out_size, void* d_ws, size_t ws_size,
                              hipStream_t stream) {
    const float* vecs = (const float*)d_in[0];
    const float* codebook = (const float*)d_in[1];
    float* out = (float*)d_out;

    const int nvec = in_sizes[0] / VQ_K;        // 65536
    double* cb64 = (double*)d_ws;               // 512*64 doubles (256 KB)
    float* csq32 = (float*)(cb64 + VQ_S * VQ_K);

    float* out_hat = out;
    float* out_z = out + (size_t)nvec * VQ_K;
    float* out_loss = out + out_size - 2;

    vq_prep<<<(VQ_S + 63) / 64, 64, 0, stream>>>(codebook, cb64, csq32);
    hipMemsetAsync(out_loss, 0, 2 * sizeof(float), stream);
    vq_main<<<nvec / BLOCK, BLOCK, 0, stream>>>(
        vecs, codebook, cb64, csq32, out_hat, out_z, out_loss,
        1.0 / (double)nvec);
}

// Round 4
// 438.709 us; speedup vs baseline: 1.0141x; 1.0141x over previous
//
#include <hip/hip_runtime.h>
#include <hip/hip_bf16.h>

// SimpleVectorQuantizer: vecs [16,32,128,64] f32, codebook [512,64] f32.
// Outputs (flat f32): vecs_hat [65536*64], z [65536] (as float), l_commit, l_codebook.
//
// Round 4: f32 LDS-tiled scan + top-2 gap trigger + exact-f64 rescue.
// r3 (exact-e everywhere) passed absmax 0 but ran 377 us: VGPR_Count=76 shows
// the f64 v[64] spilled to scratch; 4 waves/CU hid nothing. Here the scan is
// f32 (fits registers), codebook comes from LDS tiles, and only vectors whose
// top-2 gap <= 3 output-grid ulps (where the f32-vs-f64 e difference could
// possibly flip the argmin) are re-resolved with r3's proven exact pipeline.

#define VQ_K 64
#define VQ_S 512
#define BLOCK 256
#define TILE_S 128                 // codewords per LDS phase (32 KB)
#define NPHASE (VQ_S / TILE_S)
#define RESCUE_WAVES 8192          // 2048 blocks x 4 waves; x8 slots = 65536 cap
#define CELL 7.62939453125e-6f     // f32 ulp in [64,128) — score magnitude
#define GAP_THRESH (3.0f * CELL)

// K1: csq32[s] = (float) sum_k c[s][k]^2  (exact f64 accumulation)
__global__ void vq_prep(const float* __restrict__ cb, float* __restrict__ csq32) {
    int s = blockIdx.x * 64 + threadIdx.x;
    if (s >= VQ_S) return;
    const float* row = cb + (size_t)s * VQ_K;
    double acc = 0.0;
#pragma unroll
    for (int k = 0; k < VQ_K; ++k) { double c = (double)row[k]; acc = fma(c, c, acc); }
    csq32[s] = (float)acc;
}

// K2: f32 scan, one thread per vector.
__global__ __launch_bounds__(BLOCK, 1) void vq_main(
    const float* __restrict__ vecs, const float* __restrict__ codebook,
    const float* __restrict__ csq32,
    float* __restrict__ out_hat, float* __restrict__ out_z,
    float* __restrict__ out_loss,          // 2 floats, pre-zeroed
    int* __restrict__ flag_count, int* __restrict__ flag_list,
    double inv_n) {
    __shared__ float cbt[TILE_S * VQ_K];   // 32 KB codebook tile
    __shared__ int zsh[BLOCK];
    const int tid = threadIdx.x;
    const int vec = blockIdx.x * BLOCK + tid;

    // Vector in f32 registers (64 VGPRs).
    float v[VQ_K];
    {
        const float4* vp = (const float4*)(vecs + (size_t)vec * VQ_K);
#pragma unroll
        for (int i = 0; i < VQ_K / 4; ++i) {
            float4 t = vp[i];
            v[4 * i + 0] = t.x; v[4 * i + 1] = t.y;
            v[4 * i + 2] = t.z; v[4 * i + 3] = t.w;
        }
    }
    // vsq exact-f64 -> f32 (matches r3's proven choice).
    double vsq64 = 0.0;
#pragma unroll
    for (int k = 0; k < VQ_K; ++k) { double d = (double)v[k]; vsq64 = fma(d, d, vsq64); }
    const float vsq = (float)vsq64;

    float t1s = 3.4e38f, t2s = 3.4e38f;    // top-2 (score, index)
    int t1i = 0, t2i = 0;

    for (int p = 0; p < NPHASE; ++p) {
        __syncthreads();
        // Stage 128 codewords (8192 floats = 2048 float4) cooperatively.
        const float4* src = (const float4*)(codebook + (size_t)p * TILE_S * VQ_K);
        float4* dst = (float4*)cbt;
#pragma unroll
        for (int i = 0; i < 2048 / BLOCK; ++i)
            dst[i * BLOCK + tid] = src[i * BLOCK + tid];
        __syncthreads();

        for (int g = 0; g < TILE_S; g += 4) {
            const float* c0 = cbt + (size_t)(g + 0) * VQ_K;
            const float* c1 = cbt + (size_t)(g + 1) * VQ_K;
            const float* c2 = cbt + (size_t)(g + 2) * VQ_K;
            const float* c3 = cbt + (size_t)(g + 3) * VQ_K;
            float a0 = 0.f, a1 = 0.f, a2 = 0.f, a3 = 0.f;
#pragma unroll
            for (int k = 0; k < VQ_K; ++k) {
                float vk = v[k];
                a0 = fmaf(c0[k], vk, a0);
                a1 = fmaf(c1[k], vk, a1);
                a2 = fmaf(c2[k], vk, a2);
                a3 = fmaf(c3[k], vk, a3);
            }
            const int sb = p * TILE_S + g;
            // score = fl32(fl32(vsq - 2e) + csq); fma(-2,e,vsq) == fl(vsq-2e).
            float s0 = fmaf(-2.0f, a0, vsq) + csq32[sb + 0];
            float s1 = fmaf(-2.0f, a1, vsq) + csq32[sb + 1];
            float s2 = fmaf(-2.0f, a2, vsq) + csq32[sb + 2];
            float s3 = fmaf(-2.0f, a3, vsq) + csq32[sb + 3];
#define TOP2(sv, si)                                                     \
            { bool b1 = (sv) < t1s; bool b2 = (sv) < t2s;                \
              t2s = b1 ? t1s : (b2 ? (sv) : t2s);                        \
              t2i = b1 ? t1i : (b2 ? (si) : t2i);                        \
              t1s = b1 ? (sv) : t1s; t1i = b1 ? (si) : t1i; }
            TOP2(s0, sb + 0) TOP2(s1, sb + 1) TOP2(s2, sb + 2) TOP2(s3, sb + 3)
#undef TOP2
        }
    }

    // Loss from scan best (error <= ~2 grid ulps — far under threshold).
    double d = (double)(t1s < 0.0f ? 0.0f : t1s) * inv_n;
#pragma unroll
    for (int off = 32; off >= 1; off >>= 1) d += __shfl_down(d, off, 64);
    if ((tid & 63) == 0) {
        float df = (float)d;
        atomicAdd(&out_loss[0], df);
        atomicAdd(&out_loss[1], df);
    }

    out_z[vec] = (float)t1i;

    // Ambiguous argmin -> queue for exact rescue.
    if (t2s - t1s <= GAP_THRESH) {
        int pos = atomicAdd(flag_count, 1);
        flag_list[pos] = vec;
    }

    // Coalesced gather of vecs_hat (rescued vectors overwritten by K3).
    zsh[tid] = t1i;
    __syncthreads();
    const float4* cb4 = (const float4*)codebook;
    float4* hat4 = (float4*)(out_hat + (size_t)blockIdx.x * BLOCK * VQ_K);
    const int F = BLOCK * (VQ_K / 4);
#pragma unroll
    for (int f = tid; f < F; f += BLOCK) {
        int vloc = f >> 4;
        int k4 = f & 15;
        hat4[f] = cb4[zsh[vloc] * (VQ_K / 4) + k4];
    }
}

// K3: exact rescue — one wave per flagged vector, r3's proven arithmetic.
__global__ __launch_bounds__(BLOCK, 1) void vq_rescue(
    const float* __restrict__ vecs, const float* __restrict__ codebook,
    const float* __restrict__ csq32, const int* __restrict__ flag_count,
    const int* __restrict__ flag_list,
    float* __restrict__ out_hat, float* __restrict__ out_z) {
    const int lane = threadIdx.x & 63;
    const int wave = blockIdx.x * (BLOCK / 64) + (threadIdx.x >> 6);
    const int count = *flag_count;
    for (int slot = wave; slot < count; slot += RESCUE_WAVES) {
        const int vec = flag_list[slot];
        const float* vrow = vecs + (size_t)vec * VQ_K;   // wave-uniform -> s_load
        float vv[VQ_K];
#pragma unroll
        for (int k = 0; k < VQ_K; ++k) vv[k] = vrow[k];
        double vsq64 = 0.0;
#pragma unroll
        for (int k = 0; k < VQ_K; ++k) { double dd = (double)vv[k]; vsq64 = fma(dd, dd, vsq64); }
        const float vsq = (float)vsq64;

        unsigned long long best = ~0ull;
        for (int j = 0; j < 8; ++j) {            // lane's 8 codewords, ascending
            int s = lane * 8 + j;
            const float4* crow = (const float4*)(codebook + (size_t)s * VQ_K);
            double acc = 0.0;
#pragma unroll
            for (int q = 0; q < VQ_K / 4; ++q) {
                float4 c = crow[q];
                acc = fma((double)c.x, (double)vv[4 * q + 0], acc);
                acc = fma((double)c.y, (double)vv[4 * q + 1], acc);
                acc = fma((double)c.z, (double)vv[4 * q + 2], acc);
                acc = fma((double)c.w, (double)vv[4 * q + 3], acc);
            }
            float e = (float)acc;
            float sc = fmaf(-2.0f, e, vsq) + csq32[s];
            unsigned int u = __float_as_uint(sc);
            unsigned int mono = (u & 0x80000000u) ? ~u : (u | 0x80000000u);
            unsigned long long pk = ((unsigned long long)mono << 32) | (unsigned)s;
            best = pk < best ? pk : best;        // ties: smaller s wins (low bits)
        }
#pragma unroll
        for (int off = 32; off >= 1; off >>= 1) {
            unsigned long long o = __shfl_down(best, off, 64);
            best = o < best ? o : best;
        }
        best = __shfl(best, 0, 64);
        int bidx = (int)(best & 0xFFFFFFFFull);
        if (lane == 0) out_z[vec] = (float)bidx;
        out_hat[(size_t)vec * VQ_K + lane] = codebook[(size_t)bidx * VQ_K + lane];
    }
}

extern "C" void kernel_launch(void* const* d_in, const int* in_sizes, int n_in,
                              void* d_out, int out_size, void* d_ws, size_t ws_size,
                              hipStream_t stream) {
    const float* vecs = (const float*)d_in[0];
    const float* codebook = (const float*)d_in[1];
    float* out = (float*)d_out;

    const int nvec = in_sizes[0] / VQ_K;            // 65536
    int* flag_count = (int*)d_ws;                   // [0]
    int* flag_list = (int*)d_ws + 16;               // 65536 ints
    float* csq32 = (float*)((int*)d_ws + 16 + 65536);

    float* out_hat = out;
    float* out_z = out + (size_t)nvec * VQ_K;
    float* out_loss = out + out_size - 2;

    hipMemsetAsync(flag_count, 0, sizeof(int), stream);
    hipMemsetAsync(out_loss, 0, 2 * sizeof(float), stream);
    vq_prep<<<(VQ_S + 63) / 64, 64, 0, stream>>>(codebook, csq32);
    vq_main<<<nvec / BLOCK, BLOCK, 0, stream>>>(
        vecs, codebook, csq32, out_hat, out_z, out_loss,
        flag_count, flag_list, 1.0 / (double)nvec);
    vq_rescue<<<RESCUE_WAVES / (BLOCK / 64), BLOCK, 0, stream>>>(
        vecs, codebook, csq32, flag_count, flag_list, out_hat, out_z);
}

// Round 5
// 294.499 us; speedup vs baseline: 1.5107x; 1.4897x over previous
//
#include <hip/hip_runtime.h>
#include <hip/hip_bf16.h>
#include <stdint.h>

// SimpleVectorQuantizer: vecs [16,32,128,64] f32, codebook [512,64] f32.
// Outputs (flat f32): vecs_hat [65536*64], z [65536] (as float), l_commit, l_codebook.
//
// Round 5: MFMA bf16-split GEMM scan + top-2 gap trigger + exact-f64 rescue.
// r4 was LDS-issue-bound (broadcast ds_read per FMA operand, ~8192 b128/wave).
// Scores are a 65536x512x64 GEMM: split v=vh+vl, c=ch+cl (bf16), compute
// hh+hl+lh via 6 mfma_f32_16x16x32_bf16 per 16x16 tile (|score err| <~ 6e-6,
// under one f32 grid cell 7.6e-6). Vectors whose top-2 gap <= 8 cells go to
// the exact-f64 rescue (r3/r4-proven arithmetic, absmax 0).

#define VQ_K 64
#define VQ_S 512
#define BLOCK 256
#define PHASES 4
#define NT_PER_PHASE 8                   // 8 n-tiles of 16 codewords per phase
#define ROWB 272                         // B-image row: 64 hi bf16 + 64 lo bf16 + 16 pad
#define PHASE_BYTES (NT_PER_PHASE * 16 * ROWB)   // 34816
#define CSQ_OFF (VQ_S * ROWB)            // 139264
#define CELL 7.62939453125e-6f           // f32 ulp at score magnitude ~64
#define GAP_THRESH (8.0f * CELL)
#define RESCUE_BLOCKS 512
#define RESCUE_WAVES (RESCUE_BLOCKS * (BLOCK / 64))

typedef __attribute__((ext_vector_type(8))) short bf16x8;
typedef __attribute__((ext_vector_type(4))) float f32x4;

static __device__ __forceinline__ unsigned short f2bf_rne(float f) {
    unsigned u = __float_as_uint(f);
    unsigned r = (u + 0x7fffu + ((u >> 16) & 1u)) >> 16;
    return (unsigned short)r;
}
static __device__ __forceinline__ float bf2f(unsigned short h) {
    return __uint_as_float(((unsigned)h) << 16);
}

// K1: build B image: per row n: [64 x hi bf16][64 x lo bf16][16 B pad];
// csq32 (exact f64 sum -> f32) appended at CSQ_OFF.
__global__ void vq_prep(const float* __restrict__ cb, unsigned char* __restrict__ bimg) {
    int s = blockIdx.x * 64 + threadIdx.x;
    if (s >= VQ_S) return;
    const float4* src = (const float4*)(cb + (size_t)s * VQ_K);
    float v[VQ_K];
#pragma unroll
    for (int i = 0; i < VQ_K / 4; ++i) {
        float4 t = src[i];
        v[4 * i + 0] = t.x; v[4 * i + 1] = t.y;
        v[4 * i + 2] = t.z; v[4 * i + 3] = t.w;
    }
    double acc = 0.0;
    unsigned short hi[VQ_K], lo[VQ_K];
#pragma unroll
    for (int k = 0; k < VQ_K; ++k) {
        double c = (double)v[k];
        acc = fma(c, c, acc);
        unsigned short h = f2bf_rne(v[k]);
        hi[k] = h;
        lo[k] = f2bf_rne(v[k] - bf2f(h));   // v - bf(v) is exact (Sterbenz)
    }
    unsigned* wp = (unsigned*)(bimg + (size_t)s * ROWB);
#pragma unroll
    for (int i = 0; i < 32; ++i) {
        wp[i]      = (unsigned)hi[2 * i] | ((unsigned)hi[2 * i + 1] << 16);
        wp[32 + i] = (unsigned)lo[2 * i] | ((unsigned)lo[2 * i + 1] << 16);
    }
    ((float*)(bimg + CSQ_OFF))[s] = (float)acc;
}

// K2: MFMA scan. Block = 256 vectors (4 waves x 4 m-tiles of 16).
__global__ __launch_bounds__(BLOCK, 1) void vq_mfma(
    const float* __restrict__ vecs, const float* __restrict__ codebook,
    const unsigned char* __restrict__ bimg,
    float* __restrict__ out_hat, float* __restrict__ out_z,
    float* __restrict__ out_loss,
    int* __restrict__ flag_count, int* __restrict__ flag_list, float inv_n) {
    __shared__ unsigned char ldsB[PHASE_BYTES];   // 34816 B
    __shared__ float csq_sh[VQ_S];                // 2 KB
    __shared__ float vsq_sh[4][16];
    __shared__ int zsh[BLOCK];

    const int tid = threadIdx.x;
    const int wave = tid >> 6;
    const int lane = tid & 63;
    const int m = lane & 15;       // fragment row/col within tile
    const int q = lane >> 4;       // quad
    const int blockbase = blockIdx.x * BLOCK;
    const int wavebase = blockbase + wave * 64;

    // ---- A fragments (bf16 split) + vsq (exact f64 -> f32) ----
    bf16x8 ah1[4], ah2[4], al1[4], al2[4];  // hi/lo, k-windows [8q,8q+8) and [32+8q,...)
    f32x4 vsqf[4];
#pragma unroll
    for (int mt = 0; mt < 4; ++mt) {
        const float* vp = vecs + (size_t)(wavebase + mt * 16 + m) * VQ_K + q * 8;
        float4 a0 = ((const float4*)vp)[0];
        float4 a1 = ((const float4*)vp)[1];
        float4 b0 = ((const float4*)(vp + 32))[0];
        float4 b1 = ((const float4*)(vp + 32))[1];
        float w1[8] = {a0.x, a0.y, a0.z, a0.w, a1.x, a1.y, a1.z, a1.w};
        float w2[8] = {b0.x, b0.y, b0.z, b0.w, b1.x, b1.y, b1.z, b1.w};
        double p = 0.0;
#pragma unroll
        for (int j = 0; j < 8; ++j) {
            double d1 = (double)w1[j], d2 = (double)w2[j];
            p = fma(d1, d1, p); p = fma(d2, d2, p);
        }
        p += __shfl_xor(p, 16, 64);     // quads hold disjoint k-windows:
        p += __shfl_xor(p, 32, 64);     // sum over 4 quads = full ||v||^2
        if (q == 0) vsq_sh[wave][m] = (float)p;
#pragma unroll
        for (int j = 0; j < 8; ++j) {
            unsigned short h1 = f2bf_rne(w1[j]);
            unsigned short h2 = f2bf_rne(w2[j]);
            ah1[mt][j] = (short)h1;
            ah2[mt][j] = (short)h2;
            al1[mt][j] = (short)f2bf_rne(w1[j] - bf2f(h1));
            al2[mt][j] = (short)f2bf_rne(w2[j] - bf2f(h2));
        }
        // read back vsq for this lane's 4 C-rows (row = q*4 + r)
        vsqf[mt] = *(const f32x4*)&vsq_sh[wave][q * 4];
    }

    float t1s[16], t2s[16];
    int t1i[16];
#pragma unroll
    for (int st = 0; st < 16; ++st) { t1s[st] = 3.4e38f; t2s[st] = 3.4e38f; t1i[st] = 0; }
    const f32x4 zero4 = {0.f, 0.f, 0.f, 0.f};
    const unsigned char* ldsrow = ldsB + m * ROWB + q * 16;

    for (int p = 0; p < PHASES; ++p) {
        __syncthreads();   // safe LDS reuse
        {
            const float4* src = (const float4*)(bimg + (size_t)p * PHASE_BYTES);
            float4* dst = (float4*)ldsB;
            float4 tmp[9];
#pragma unroll
            for (int j = 0; j < 9; ++j) { int i = tid + j * 256; if (i < PHASE_BYTES / 16) tmp[j] = src[i]; }
#pragma unroll
            for (int j = 0; j < 9; ++j) { int i = tid + j * 256; if (i < PHASE_BYTES / 16) dst[i] = tmp[j]; }
            if (p == 0 && tid < 128)
                ((float4*)csq_sh)[tid] = ((const float4*)(bimg + CSQ_OFF))[tid];
        }
        __syncthreads();

#pragma unroll
        for (int t = 0; t < NT_PER_PHASE; ++t) {
            const int nbase = p * 128 + t * 16;
            const float csqn = csq_sh[nbase + m];
            const int nidx = nbase + m;
            bf16x8 bh1 = *(const bf16x8*)(ldsrow + t * 16 * ROWB);
            bf16x8 bh2 = *(const bf16x8*)(ldsrow + t * 16 * ROWB + 64);
            bf16x8 bl1 = *(const bf16x8*)(ldsrow + t * 16 * ROWB + 128);
            bf16x8 bl2 = *(const bf16x8*)(ldsrow + t * 16 * ROWB + 192);
#pragma unroll
            for (int mt = 0; mt < 4; ++mt) {
                f32x4 acc = __builtin_amdgcn_mfma_f32_16x16x32_bf16(ah1[mt], bh1, zero4, 0, 0, 0);
                acc = __builtin_amdgcn_mfma_f32_16x16x32_bf16(ah2[mt], bh2, acc, 0, 0, 0);
                acc = __builtin_amdgcn_mfma_f32_16x16x32_bf16(ah1[mt], bl1, acc, 0, 0, 0);
                acc = __builtin_amdgcn_mfma_f32_16x16x32_bf16(ah2[mt], bl2, acc, 0, 0, 0);
                acc = __builtin_amdgcn_mfma_f32_16x16x32_bf16(al1[mt], bh1, acc, 0, 0, 0);
                acc = __builtin_amdgcn_mfma_f32_16x16x32_bf16(al2[mt], bh2, acc, 0, 0, 0);
#pragma unroll
                for (int r = 0; r < 4; ++r) {
                    // ref outer arithmetic: fl32(fl32(vsq-2e)+csq)
                    float sc = fmaf(-2.0f, acc[r], vsqf[mt][r]) + csqn;
                    const int st = mt * 4 + r;
                    bool b1 = sc < t1s[st];
                    bool b2 = sc < t2s[st];
                    t2s[st] = b1 ? t1s[st] : (b2 ? sc : t2s[st]);
                    t1s[st] = b1 ? sc : t1s[st];
                    t1i[st] = b1 ? nidx : t1i[st];
                }
            }
        }
    }

    // ---- cross-lane merge over the 16 cols (lanes sharing a quad group) ----
    unsigned long long pk[16];
#pragma unroll
    for (int st = 0; st < 16; ++st) {
        unsigned u = __float_as_uint(t1s[st]);
        unsigned mono = (u & 0x80000000u) ? ~u : (u | 0x80000000u);
        pk[st] = ((unsigned long long)mono << 32) | (unsigned)t1i[st];
    }
#pragma unroll
    for (int dd = 1; dd <= 8; dd <<= 1) {
#pragma unroll
        for (int st = 0; st < 16; ++st) {
            unsigned long long opk = __shfl_xor(pk[st], dd, 64);
            float o1 = __shfl_xor(t1s[st], dd, 64);
            float o2 = __shfl_xor(t2s[st], dd, 64);
            t2s[st] = fminf(fmaxf(t1s[st], o1), fminf(t2s[st], o2));
            t1s[st] = fminf(t1s[st], o1);
            pk[st] = opk < pk[st] ? opk : pk[st];   // ties -> smaller index
        }
    }

    // writer: lane (q, i=m) owns state st=i -> vector (mt=i>>2, row=q*4+(i&3))
    const int st = m;
    const int vloc = ((m >> 2) * 16) + q * 4 + (m & 3) + wave * 64;
    const int gvec = blockbase + vloc;
    const int bidx = (int)(pk[st] & 0xffffffffull);
    out_z[gvec] = (float)bidx;
    zsh[vloc] = bidx;
    if (t2s[st] - t1s[st] <= GAP_THRESH) {
        int pos = atomicAdd(flag_count, 1);
        flag_list[pos] = gvec;
    }
    float dl = (t1s[st] < 0.f ? 0.f : t1s[st]) * inv_n;
#pragma unroll
    for (int off = 32; off >= 1; off >>= 1) dl += __shfl_down(dl, off, 64);
    if (lane == 0) { atomicAdd(&out_loss[0], dl); atomicAdd(&out_loss[1], dl); }

    __syncthreads();
    const float4* cb4 = (const float4*)codebook;
    float4* hat4 = (float4*)(out_hat + (size_t)blockIdx.x * BLOCK * VQ_K);
    const int F = BLOCK * (VQ_K / 4);
#pragma unroll
    for (int f = tid; f < F; f += BLOCK) {
        int vv = f >> 4;
        int k4 = f & 15;
        hat4[f] = cb4[zsh[vv] * (VQ_K / 4) + k4];
    }
}

// K3: exact rescue (r3/r4-proven arithmetic) for flagged vectors.
__global__ __launch_bounds__(BLOCK, 1) void vq_rescue(
    const float* __restrict__ vecs, const float* __restrict__ codebook,
    const unsigned char* __restrict__ bimg, const int* __restrict__ flag_count,
    const int* __restrict__ flag_list,
    float* __restrict__ out_hat, float* __restrict__ out_z) {
    const float* csq32 = (const float*)(bimg + CSQ_OFF);
    const int lane = threadIdx.x & 63;
    const int wave = blockIdx.x * (BLOCK / 64) + (threadIdx.x >> 6);
    const int count = *flag_count;
    for (int slot = wave; slot < count; slot += RESCUE_WAVES) {
        const int vec = flag_list[slot];
        const float4* vrow4 = (const float4*)(vecs + (size_t)vec * VQ_K);
        float vv[VQ_K];
#pragma unroll
        for (int i = 0; i < VQ_K / 4; ++i) {
            float4 t = vrow4[i];
            vv[4 * i + 0] = t.x; vv[4 * i + 1] = t.y;
            vv[4 * i + 2] = t.z; vv[4 * i + 3] = t.w;
        }
        double vsq64 = 0.0;
#pragma unroll
        for (int k = 0; k < VQ_K; ++k) { double d = (double)vv[k]; vsq64 = fma(d, d, vsq64); }
        const float vsq = (float)vsq64;

        unsigned long long best = ~0ull;
        for (int j = 0; j < 8; ++j) {
            int s = lane * 8 + j;
            const float4* crow = (const float4*)(codebook + (size_t)s * VQ_K);
            double acc = 0.0;
#pragma unroll
            for (int qq = 0; qq < VQ_K / 4; ++qq) {
                float4 c = crow[qq];
                acc = fma((double)c.x, (double)vv[4 * qq + 0], acc);
                acc = fma((double)c.y, (double)vv[4 * qq + 1], acc);
                acc = fma((double)c.z, (double)vv[4 * qq + 2], acc);
                acc = fma((double)c.w, (double)vv[4 * qq + 3], acc);
            }
            float e = (float)acc;
            float sc = fmaf(-2.0f, e, vsq) + csq32[s];
            unsigned u = __float_as_uint(sc);
            unsigned mono = (u & 0x80000000u) ? ~u : (u | 0x80000000u);
            unsigned long long pk = ((unsigned long long)mono << 32) | (unsigned)s;
            best = pk < best ? pk : best;
        }
#pragma unroll
        for (int off = 32; off >= 1; off >>= 1) {
            unsigned long long o = __shfl_down(best, off, 64);
            best = o < best ? o : best;
        }
        best = __shfl(best, 0, 64);
        int bidx = (int)(best & 0xffffffffull);
        if (lane == 0) out_z[vec] = (float)bidx;
        out_hat[(size_t)vec * VQ_K + lane] = codebook[(size_t)bidx * VQ_K + lane];
    }
}

extern "C" void kernel_launch(void* const* d_in, const int* in_sizes, int n_in,
                              void* d_out, int out_size, void* d_ws, size_t ws_size,
                              hipStream_t stream) {
    const float* vecs = (const float*)d_in[0];
    const float* codebook = (const float*)d_in[1];
    float* out = (float*)d_out;

    const int nvec = in_sizes[0] / VQ_K;            // 65536
    int* flag_count = (int*)d_ws;
    int* flag_list = (int*)d_ws + 16;               // 65536 ints
    unsigned char* bimg = (unsigned char*)d_ws + 262400;  // 141312 B image

    float* out_hat = out;
    float* out_z = out + (size_t)nvec * VQ_K;
    float* out_loss = out + out_size - 2;

    hipMemsetAsync(flag_count, 0, sizeof(int), stream);
    hipMemsetAsync(out_loss, 0, 2 * sizeof(float), stream);
    vq_prep<<<(VQ_S + 63) / 64, 64, 0, stream>>>(codebook, bimg);
    vq_mfma<<<nvec / BLOCK, BLOCK, 0, stream>>>(
        vecs, codebook, bimg, out_hat, out_z, out_loss,
        flag_count, flag_list, 1.0f / (float)nvec);
    vq_rescue<<<RESCUE_BLOCKS, BLOCK, 0, stream>>>(
        vecs, codebook, bimg, flag_count, flag_list, out_hat, out_z);
}

// Round 6
// 148.960 us; speedup vs baseline: 2.9868x; 1.9770x over previous
//
#include <hip/hip_runtime.h>
#include <hip/hip_bf16.h>
#include <stdint.h>

// SimpleVectorQuantizer: vecs [16,32,128,64] f32, codebook [512,64] f32.
// Outputs (flat f32): vecs_hat [65536*64], z [65536] (as float), l_commit, l_codebook.
//
// Round 6: r5's MFMA bf16-split scan (absmax 0, proven) with the exact-f64
// rescue folded INTO the block epilogue. r5's separate rescue dispatch cost
// ~185 us at 0.06% VALUBusy — a latency-only dispatch (few live waves, serial
// f64 chains, plus it absorbed the mfma kernel's L2 writeback window).
// Flag rate is ~6e-4 (gap <= 8 f32-grid cells), i.e. ~0.15 vectors per block
// of 256 — block-local rescue costs ~2 us amortized and removes the dispatch.

#define VQ_K 64
#define VQ_S 512
#define BLOCK 256
#define PHASES 4
#define NT_PER_PHASE 8                   // 8 n-tiles of 16 codewords per phase
#define ROWB 272                         // B-image row: 64 hi bf16 + 64 lo bf16 + 16 pad
#define PHASE_BYTES (NT_PER_PHASE * 16 * ROWB)   // 34816
#define CSQ_OFF (VQ_S * ROWB)            // 139264
#define CELL 7.62939453125e-6f           // f32 ulp at score magnitude ~64
#define GAP_THRESH (8.0f * CELL)

typedef __attribute__((ext_vector_type(8))) short bf16x8;
typedef __attribute__((ext_vector_type(4))) float f32x4;

static __device__ __forceinline__ unsigned short f2bf_rne(float f) {
    unsigned u = __float_as_uint(f);
    unsigned r = (u + 0x7fffu + ((u >> 16) & 1u)) >> 16;
    return (unsigned short)r;
}
static __device__ __forceinline__ float bf2f(unsigned short h) {
    return __uint_as_float(((unsigned)h) << 16);
}

// K1: B image: per row n: [64 x hi bf16][64 x lo bf16][16 B pad];
// csq32 (exact f64 sum -> f32) appended at CSQ_OFF.
__global__ void vq_prep(const float* __restrict__ cb, unsigned char* __restrict__ bimg) {
    int s = blockIdx.x * 64 + threadIdx.x;
    if (s >= VQ_S) return;
    const float4* src = (const float4*)(cb + (size_t)s * VQ_K);
    float v[VQ_K];
#pragma unroll
    for (int i = 0; i < VQ_K / 4; ++i) {
        float4 t = src[i];
        v[4 * i + 0] = t.x; v[4 * i + 1] = t.y;
        v[4 * i + 2] = t.z; v[4 * i + 3] = t.w;
    }
    double acc = 0.0;
    unsigned short hi[VQ_K], lo[VQ_K];
#pragma unroll
    for (int k = 0; k < VQ_K; ++k) {
        double c = (double)v[k];
        acc = fma(c, c, acc);
        unsigned short h = f2bf_rne(v[k]);
        hi[k] = h;
        lo[k] = f2bf_rne(v[k] - bf2f(h));
    }
    unsigned* wp = (unsigned*)(bimg + (size_t)s * ROWB);
#pragma unroll
    for (int i = 0; i < 32; ++i) {
        wp[i]      = (unsigned)hi[2 * i] | ((unsigned)hi[2 * i + 1] << 16);
        wp[32 + i] = (unsigned)lo[2 * i] | ((unsigned)lo[2 * i + 1] << 16);
    }
    ((float*)(bimg + CSQ_OFF))[s] = (float)acc;
}

// K2: MFMA scan + in-block exact rescue. Block = 256 vectors (4 waves x 4 m-tiles).
__global__ __launch_bounds__(BLOCK, 1) void vq_mfma(
    const float* __restrict__ vecs, const float* __restrict__ codebook,
    const unsigned char* __restrict__ bimg,
    float* __restrict__ out_hat, float* __restrict__ out_z,
    float* __restrict__ out_loss, float inv_n) {
    __shared__ unsigned char ldsB[PHASE_BYTES];   // 34816 B
    __shared__ float csq_sh[VQ_S];                // 2 KB
    __shared__ float vsq_all[BLOCK];              // exact ||v||^2 -> f32, per vector
    __shared__ int zsh[BLOCK];
    __shared__ int rlist[BLOCK];
    __shared__ int rn;

    const int tid = threadIdx.x;
    const int wave = tid >> 6;
    const int lane = tid & 63;
    const int m = lane & 15;
    const int q = lane >> 4;
    const int blockbase = blockIdx.x * BLOCK;
    const int wavebase = blockbase + wave * 64;

    if (tid == 0) rn = 0;   // visible via the phase-0 barrier below

    // ---- A fragments (bf16 split) + exact vsq ----
    bf16x8 ah1[4], ah2[4], al1[4], al2[4];
    f32x4 vsqf[4];
#pragma unroll
    for (int mt = 0; mt < 4; ++mt) {
        const float* vp = vecs + (size_t)(wavebase + mt * 16 + m) * VQ_K + q * 8;
        float4 a0 = ((const float4*)vp)[0];
        float4 a1 = ((const float4*)vp)[1];
        float4 b0 = ((const float4*)(vp + 32))[0];
        float4 b1 = ((const float4*)(vp + 32))[1];
        float w1[8] = {a0.x, a0.y, a0.z, a0.w, a1.x, a1.y, a1.z, a1.w};
        float w2[8] = {b0.x, b0.y, b0.z, b0.w, b1.x, b1.y, b1.z, b1.w};
        double p = 0.0;
#pragma unroll
        for (int j = 0; j < 8; ++j) {
            double d1 = (double)w1[j], d2 = (double)w2[j];
            p = fma(d1, d1, p); p = fma(d2, d2, p);
        }
        p += __shfl_xor(p, 16, 64);
        p += __shfl_xor(p, 32, 64);
        if (q == 0) vsq_all[wave * 64 + mt * 16 + m] = (float)p;
#pragma unroll
        for (int j = 0; j < 8; ++j) {
            unsigned short h1 = f2bf_rne(w1[j]);
            unsigned short h2 = f2bf_rne(w2[j]);
            ah1[mt][j] = (short)h1;
            ah2[mt][j] = (short)h2;
            al1[mt][j] = (short)f2bf_rne(w1[j] - bf2f(h1));
            al2[mt][j] = (short)f2bf_rne(w2[j] - bf2f(h2));
        }
        vsqf[mt] = *(const f32x4*)&vsq_all[wave * 64 + mt * 16 + q * 4];
    }

    float t1s[16], t2s[16];
    int t1i[16];
#pragma unroll
    for (int st = 0; st < 16; ++st) { t1s[st] = 3.4e38f; t2s[st] = 3.4e38f; t1i[st] = 0; }
    const f32x4 zero4 = {0.f, 0.f, 0.f, 0.f};
    const unsigned char* ldsrow = ldsB + m * ROWB + q * 16;

    for (int p = 0; p < PHASES; ++p) {
        __syncthreads();
        {
            const float4* src = (const float4*)(bimg + (size_t)p * PHASE_BYTES);
            float4* dst = (float4*)ldsB;
            float4 tmp[9];
#pragma unroll
            for (int j = 0; j < 9; ++j) { int i = tid + j * 256; if (i < PHASE_BYTES / 16) tmp[j] = src[i]; }
#pragma unroll
            for (int j = 0; j < 9; ++j) { int i = tid + j * 256; if (i < PHASE_BYTES / 16) dst[i] = tmp[j]; }
            if (p == 0 && tid < 128)
                ((float4*)csq_sh)[tid] = ((const float4*)(bimg + CSQ_OFF))[tid];
        }
        __syncthreads();

#pragma unroll
        for (int t = 0; t < NT_PER_PHASE; ++t) {
            const int nbase = p * 128 + t * 16;
            const float csqn = csq_sh[nbase + m];
            const int nidx = nbase + m;
            bf16x8 bh1 = *(const bf16x8*)(ldsrow + t * 16 * ROWB);
            bf16x8 bh2 = *(const bf16x8*)(ldsrow + t * 16 * ROWB + 64);
            bf16x8 bl1 = *(const bf16x8*)(ldsrow + t * 16 * ROWB + 128);
            bf16x8 bl2 = *(const bf16x8*)(ldsrow + t * 16 * ROWB + 192);
#pragma unroll
            for (int mt = 0; mt < 4; ++mt) {
                f32x4 acc = __builtin_amdgcn_mfma_f32_16x16x32_bf16(ah1[mt], bh1, zero4, 0, 0, 0);
                acc = __builtin_amdgcn_mfma_f32_16x16x32_bf16(ah2[mt], bh2, acc, 0, 0, 0);
                acc = __builtin_amdgcn_mfma_f32_16x16x32_bf16(ah1[mt], bl1, acc, 0, 0, 0);
                acc = __builtin_amdgcn_mfma_f32_16x16x32_bf16(ah2[mt], bl2, acc, 0, 0, 0);
                acc = __builtin_amdgcn_mfma_f32_16x16x32_bf16(al1[mt], bh1, acc, 0, 0, 0);
                acc = __builtin_amdgcn_mfma_f32_16x16x32_bf16(al2[mt], bh2, acc, 0, 0, 0);
#pragma unroll
                for (int r = 0; r < 4; ++r) {
                    float sc = fmaf(-2.0f, acc[r], vsqf[mt][r]) + csqn;
                    const int st = mt * 4 + r;
                    bool b1 = sc < t1s[st];
                    bool b2 = sc < t2s[st];
                    t2s[st] = b1 ? t1s[st] : (b2 ? sc : t2s[st]);
                    t1s[st] = b1 ? sc : t1s[st];
                    t1i[st] = b1 ? nidx : t1i[st];
                }
            }
        }
    }

    // ---- butterfly merge over the 16 cols ----
    unsigned long long pk[16];
#pragma unroll
    for (int st = 0; st < 16; ++st) {
        unsigned u = __float_as_uint(t1s[st]);
        unsigned mono = (u & 0x80000000u) ? ~u : (u | 0x80000000u);
        pk[st] = ((unsigned long long)mono << 32) | (unsigned)t1i[st];
    }
#pragma unroll
    for (int dd = 1; dd <= 8; dd <<= 1) {
#pragma unroll
        for (int st = 0; st < 16; ++st) {
            unsigned long long opk = __shfl_xor(pk[st], dd, 64);
            float o1 = __shfl_xor(t1s[st], dd, 64);
            float o2 = __shfl_xor(t2s[st], dd, 64);
            t2s[st] = fminf(fmaxf(t1s[st], o1), fminf(t2s[st], o2));
            t1s[st] = fminf(t1s[st], o1);
            pk[st] = opk < pk[st] ? opk : pk[st];
        }
    }

    // ---- writers: each thread owns one vector ----
    const int st = m;
    const int vloc = ((m >> 2) * 16) + q * 4 + (m & 3) + wave * 64;
    const int bidx = (int)(pk[st] & 0xffffffffull);
    zsh[vloc] = bidx;
    if (t2s[st] - t1s[st] <= GAP_THRESH) {
        int pos = atomicAdd(&rn, 1);
        rlist[pos] = vloc;
    }
    float dl = (t1s[st] < 0.f ? 0.f : t1s[st]) * inv_n;
#pragma unroll
    for (int off = 32; off >= 1; off >>= 1) dl += __shfl_down(dl, off, 64);
    if (lane == 0) { atomicAdd(&out_loss[0], dl); atomicAdd(&out_loss[1], dl); }

    __syncthreads();

    // ---- in-block exact rescue: wave w handles rlist[i*4+w] ----
    const int nr = rn;
    for (int base = 0; base < nr; base += 4) {
        const int slot = base + wave;
        if (slot < nr) {                       // wave-uniform condition
            const int rv = rlist[slot];
            const float4* vrow4 = (const float4*)(vecs + (size_t)(blockbase + rv) * VQ_K);
            const float vsqr = vsq_all[rv];
            unsigned long long best = ~0ull;
            for (int j = 0; j < 8; ++j) {      // lane's 8 codewords, ascending
                const int s = lane * 8 + j;
                const float4* crow = (const float4*)(codebook + (size_t)s * VQ_K);
                double acc = 0.0;
#pragma unroll
                for (int qq = 0; qq < VQ_K / 4; ++qq) {
                    float4 c = crow[qq];
                    float4 t = vrow4[qq];      // wave-uniform -> scalar loads
                    acc = fma((double)c.x, (double)t.x, acc);
                    acc = fma((double)c.y, (double)t.y, acc);
                    acc = fma((double)c.z, (double)t.z, acc);
                    acc = fma((double)c.w, (double)t.w, acc);
                }
                float e = (float)acc;
                float sc = fmaf(-2.0f, e, vsqr) + csq_sh[s];
                unsigned u = __float_as_uint(sc);
                unsigned mono = (u & 0x80000000u) ? ~u : (u | 0x80000000u);
                unsigned long long pkr = ((unsigned long long)mono << 32) | (unsigned)s;
                best = pkr < best ? pkr : best;
            }
#pragma unroll
            for (int off = 32; off >= 1; off >>= 1) {
                unsigned long long o = __shfl_down(best, off, 64);
                best = o < best ? o : best;
            }
            if (lane == 0) zsh[rv] = (int)(best & 0xffffffffull);
        }
    }
    __syncthreads();

    // ---- coalesced z write + gather ----
    out_z[blockbase + tid] = (float)zsh[tid];
    const float4* cb4 = (const float4*)codebook;
    float4* hat4 = (float4*)(out_hat + (size_t)blockIdx.x * BLOCK * VQ_K);
    const int F = BLOCK * (VQ_K / 4);
#pragma unroll
    for (int f = tid; f < F; f += BLOCK) {
        int vv = f >> 4;
        int k4 = f & 15;
        hat4[f] = cb4[zsh[vv] * (VQ_K / 4) + k4];
    }
}

extern "C" void kernel_launch(void* const* d_in, const int* in_sizes, int n_in,
                              void* d_out, int out_size, void* d_ws, size_t ws_size,
                              hipStream_t stream) {
    const float* vecs = (const float*)d_in[0];
    const float* codebook = (const float*)d_in[1];
    float* out = (float*)d_out;

    const int nvec = in_sizes[0] / VQ_K;            // 65536
    unsigned char* bimg = (unsigned char*)d_ws;     // 141312 B image

    float* out_hat = out;
    float* out_z = out + (size_t)nvec * VQ_K;
    float* out_loss = out + out_size - 2;

    hipMemsetAsync(out_loss, 0, 2 * sizeof(float), stream);
    vq_prep<<<(VQ_S + 63) / 64, 64, 0, stream>>>(codebook, bimg);
    vq_mfma<<<nvec / BLOCK, BLOCK, 0, stream>>>(
        vecs, codebook, bimg, out_hat, out_z, out_loss, 1.0f / (float)nvec);
}

// Round 7
// 134.952 us; speedup vs baseline: 3.2968x; 1.1038x over previous
//
#include <hip/hip_runtime.h>
#include <hip/hip_bf16.h>
#include <stdint.h>

// SimpleVectorQuantizer: vecs [16,32,128,64] f32, codebook [512,64] f32.
// Outputs (flat f32): vecs_hat [65536*64], z [65536] (as float), l_commit, l_codebook.
//
// Round 7: kill the scratch spills r6's counters exposed.
//  - vq_prep (was 108 us, VGPR=64, arrays spilled): one wave per codebook row,
//    lane-per-element, f64 wave-reduce for csq. No per-thread arrays.
//  - vq_mfma (was 81 us, VGPR=96, WRITE 25.4 MB = 8 MB spill): the writer
//    indexed t1s/t2s/pk with runtime st=m -> whole arrays demoted to scratch.
//    Replaced with a static-unrolled cndmask select chain.
//  - Block = 128 vectors (2 waves), grid 512 -> 2 blocks/CU, staging of one
//    overlaps compute of the other.

#define VQ_K 64
#define VQ_S 512
#define BLOCK 128
#define PHASES 4
#define NT_PER_PHASE 8                   // 8 n-tiles of 16 codewords per phase
#define ROWB 272                         // B row: 64 hi bf16 + 64 lo bf16 + 16 pad
#define PHASE_BYTES (NT_PER_PHASE * 16 * ROWB)   // 34816
#define CSQ_OFF (VQ_S * ROWB)            // 139264
#define CELL 7.62939453125e-6f           // f32 ulp at score magnitude ~64
#define GAP_THRESH (8.0f * CELL)

typedef __attribute__((ext_vector_type(8))) short bf16x8;
typedef __attribute__((ext_vector_type(4))) float f32x4;

static __device__ __forceinline__ unsigned short f2bf_rne(float f) {
    unsigned u = __float_as_uint(f);
    unsigned r = (u + 0x7fffu + ((u >> 16) & 1u)) >> 16;
    return (unsigned short)r;
}
static __device__ __forceinline__ float bf2f(unsigned short h) {
    return __uint_as_float(((unsigned)h) << 16);
}

// K1: one wave per codebook row; lane k handles element k. No arrays.
__global__ __launch_bounds__(256, 1) void vq_prep(
    const float* __restrict__ cb, unsigned char* __restrict__ bimg) {
    const int lane = threadIdx.x & 63;
    const int row = blockIdx.x * 4 + (threadIdx.x >> 6);   // 128 blocks x 4 waves
    float c = cb[(size_t)row * VQ_K + lane];
    double d = (double)c * (double)c;
#pragma unroll
    for (int off = 1; off <= 32; off <<= 1) d += __shfl_xor(d, off, 64);
    unsigned short hi = f2bf_rne(c);
    unsigned short lo = f2bf_rne(c - bf2f(hi));   // c - bf(c) exact
    unsigned char* rowp = bimg + (size_t)row * ROWB;
    ((unsigned short*)rowp)[lane] = hi;
    ((unsigned short*)(rowp + 128))[lane] = lo;
    if (lane == 0) ((float*)(bimg + CSQ_OFF))[row] = (float)d;
}

// K2: MFMA scan + in-block exact rescue. Block = 128 vectors (2 waves x 4 m-tiles).
__global__ __launch_bounds__(BLOCK, 1) void vq_mfma(
    const float* __restrict__ vecs, const float* __restrict__ codebook,
    const unsigned char* __restrict__ bimg,
    float* __restrict__ out_hat, float* __restrict__ out_z,
    float* __restrict__ out_loss, float inv_n) {
    __shared__ unsigned char ldsB[PHASE_BYTES];   // 34816 B
    __shared__ float csq_sh[VQ_S];                // 2 KB
    __shared__ float vsq_all[BLOCK];
    __shared__ int zsh[BLOCK];
    __shared__ int rlist[BLOCK];
    __shared__ int rn;

    const int tid = threadIdx.x;
    const int wave = tid >> 6;                    // 0..1
    const int lane = tid & 63;
    const int m = lane & 15;
    const int q = lane >> 4;
    const int blockbase = blockIdx.x * BLOCK;
    const int wavebase = blockbase + wave * 64;

    if (tid == 0) rn = 0;

    // ---- A fragments (bf16 split) + exact vsq ----
    bf16x8 ah1[4], ah2[4], al1[4], al2[4];
    f32x4 vsqf[4];
#pragma unroll
    for (int mt = 0; mt < 4; ++mt) {
        const float* vp = vecs + (size_t)(wavebase + mt * 16 + m) * VQ_K + q * 8;
        float4 a0 = ((const float4*)vp)[0];
        float4 a1 = ((const float4*)vp)[1];
        float4 b0 = ((const float4*)(vp + 32))[0];
        float4 b1 = ((const float4*)(vp + 32))[1];
        float w1[8] = {a0.x, a0.y, a0.z, a0.w, a1.x, a1.y, a1.z, a1.w};
        float w2[8] = {b0.x, b0.y, b0.z, b0.w, b1.x, b1.y, b1.z, b1.w};
        double p = 0.0;
#pragma unroll
        for (int j = 0; j < 8; ++j) {
            double d1 = (double)w1[j], d2 = (double)w2[j];
            p = fma(d1, d1, p); p = fma(d2, d2, p);
        }
        p += __shfl_xor(p, 16, 64);
        p += __shfl_xor(p, 32, 64);
        if (q == 0) vsq_all[wave * 64 + mt * 16 + m] = (float)p;
#pragma unroll
        for (int j = 0; j < 8; ++j) {
            unsigned short h1 = f2bf_rne(w1[j]);
            unsigned short h2 = f2bf_rne(w2[j]);
            ah1[mt][j] = (short)h1;
            ah2[mt][j] = (short)h2;
            al1[mt][j] = (short)f2bf_rne(w1[j] - bf2f(h1));
            al2[mt][j] = (short)f2bf_rne(w2[j] - bf2f(h2));
        }
        vsqf[mt] = *(const f32x4*)&vsq_all[wave * 64 + mt * 16 + q * 4];
    }

    float t1s[16], t2s[16];
    int t1i[16];
#pragma unroll
    for (int st = 0; st < 16; ++st) { t1s[st] = 3.4e38f; t2s[st] = 3.4e38f; t1i[st] = 0; }
    const f32x4 zero4 = {0.f, 0.f, 0.f, 0.f};
    const unsigned char* ldsrow = ldsB + m * ROWB + q * 16;

    for (int p = 0; p < PHASES; ++p) {
        __syncthreads();
        {
            // 2176 float4 per phase / 128 threads = exactly 17 each.
            const float4* src = (const float4*)(bimg + (size_t)p * PHASE_BYTES);
            float4* dst = (float4*)ldsB;
            float4 tmp[17];
#pragma unroll
            for (int j = 0; j < 17; ++j) tmp[j] = src[tid + j * BLOCK];
#pragma unroll
            for (int j = 0; j < 17; ++j) dst[tid + j * BLOCK] = tmp[j];
            if (p == 0) ((float4*)csq_sh)[tid] = ((const float4*)(bimg + CSQ_OFF))[tid];
        }
        __syncthreads();

#pragma unroll
        for (int t = 0; t < NT_PER_PHASE; ++t) {
            const int nbase = p * 128 + t * 16;
            const float csqn = csq_sh[nbase + m];
            const int nidx = nbase + m;
            bf16x8 bh1 = *(const bf16x8*)(ldsrow + t * 16 * ROWB);
            bf16x8 bh2 = *(const bf16x8*)(ldsrow + t * 16 * ROWB + 64);
            bf16x8 bl1 = *(const bf16x8*)(ldsrow + t * 16 * ROWB + 128);
            bf16x8 bl2 = *(const bf16x8*)(ldsrow + t * 16 * ROWB + 192);
#pragma unroll
            for (int mt = 0; mt < 4; ++mt) {
                f32x4 acc = __builtin_amdgcn_mfma_f32_16x16x32_bf16(ah1[mt], bh1, zero4, 0, 0, 0);
                acc = __builtin_amdgcn_mfma_f32_16x16x32_bf16(ah2[mt], bh2, acc, 0, 0, 0);
                acc = __builtin_amdgcn_mfma_f32_16x16x32_bf16(ah1[mt], bl1, acc, 0, 0, 0);
                acc = __builtin_amdgcn_mfma_f32_16x16x32_bf16(ah2[mt], bl2, acc, 0, 0, 0);
                acc = __builtin_amdgcn_mfma_f32_16x16x32_bf16(al1[mt], bh1, acc, 0, 0, 0);
                acc = __builtin_amdgcn_mfma_f32_16x16x32_bf16(al2[mt], bh2, acc, 0, 0, 0);
#pragma unroll
                for (int r = 0; r < 4; ++r) {
                    float sc = fmaf(-2.0f, acc[r], vsqf[mt][r]) + csqn;
                    const int st = mt * 4 + r;
                    bool b1 = sc < t1s[st];
                    bool b2 = sc < t2s[st];
                    t2s[st] = b1 ? t1s[st] : (b2 ? sc : t2s[st]);
                    t1s[st] = b1 ? sc : t1s[st];
                    t1i[st] = b1 ? nidx : t1i[st];
                }
            }
        }
    }

    // ---- butterfly merge over the 16 cols (static indices only) ----
    unsigned long long pk[16];
#pragma unroll
    for (int st = 0; st < 16; ++st) {
        unsigned u = __float_as_uint(t1s[st]);
        unsigned mono = (u & 0x80000000u) ? ~u : (u | 0x80000000u);
        pk[st] = ((unsigned long long)mono << 32) | (unsigned)t1i[st];
    }
#pragma unroll
    for (int dd = 1; dd <= 8; dd <<= 1) {
#pragma unroll
        for (int st = 0; st < 16; ++st) {
            unsigned long long opk = __shfl_xor(pk[st], dd, 64);
            float o1 = __shfl_xor(t1s[st], dd, 64);
            float o2 = __shfl_xor(t2s[st], dd, 64);
            t2s[st] = fminf(fmaxf(t1s[st], o1), fminf(t2s[st], o2));
            t1s[st] = fminf(t1s[st], o1);
            pk[st] = opk < pk[st] ? opk : pk[st];
        }
    }

    // ---- writer: STATIC select chain (no dynamic register indexing!) ----
    float w1s = 3.4e38f, w2s = 3.4e38f;
    unsigned long long wpk = 0;
#pragma unroll
    for (int i = 0; i < 16; ++i) {
        bool sel = (m == i);
        w1s = sel ? t1s[i] : w1s;
        w2s = sel ? t2s[i] : w2s;
        wpk = sel ? pk[i] : wpk;
    }
    const int vloc = ((m >> 2) * 16) + q * 4 + (m & 3) + wave * 64;
    zsh[vloc] = (int)(wpk & 0xffffffffull);
    if (w2s - w1s <= GAP_THRESH) {
        int pos = atomicAdd(&rn, 1);
        rlist[pos] = vloc;
    }
    float dl = (w1s < 0.f ? 0.f : w1s) * inv_n;
#pragma unroll
    for (int off = 32; off >= 1; off >>= 1) dl += __shfl_down(dl, off, 64);
    if (lane == 0) { atomicAdd(&out_loss[0], dl); atomicAdd(&out_loss[1], dl); }

    __syncthreads();

    // ---- in-block exact rescue: wave w handles rlist[i*2+w] ----
    const int nr = rn;
    for (int base = 0; base < nr; base += 2) {
        const int slot = base + wave;
        if (slot < nr) {                       // wave-uniform
            const int rv = rlist[slot];
            const float4* vrow4 = (const float4*)(vecs + (size_t)(blockbase + rv) * VQ_K);
            const float vsqr = vsq_all[rv];
            unsigned long long best = ~0ull;
            for (int j = 0; j < 8; ++j) {
                const int s = lane * 8 + j;
                const float4* crow = (const float4*)(codebook + (size_t)s * VQ_K);
                double acc = 0.0;
#pragma unroll
                for (int qq = 0; qq < VQ_K / 4; ++qq) {
                    float4 c = crow[qq];
                    float4 t = vrow4[qq];      // wave-uniform -> scalar loads
                    acc = fma((double)c.x, (double)t.x, acc);
                    acc = fma((double)c.y, (double)t.y, acc);
                    acc = fma((double)c.z, (double)t.z, acc);
                    acc = fma((double)c.w, (double)t.w, acc);
                }
                float e = (float)acc;
                float sc = fmaf(-2.0f, e, vsqr) + csq_sh[s];
                unsigned u = __float_as_uint(sc);
                unsigned mono = (u & 0x80000000u) ? ~u : (u | 0x80000000u);
                unsigned long long pkr = ((unsigned long long)mono << 32) | (unsigned)s;
                best = pkr < best ? pkr : best;
            }
#pragma unroll
            for (int off = 32; off >= 1; off >>= 1) {
                unsigned long long o = __shfl_down(best, off, 64);
                best = o < best ? o : best;
            }
            if (lane == 0) zsh[rv] = (int)(best & 0xffffffffull);
        }
    }
    __syncthreads();

    // ---- coalesced z write + gather ----
    out_z[blockbase + tid] = (float)zsh[tid];
    const float4* cb4 = (const float4*)codebook;
    float4* hat4 = (float4*)(out_hat + (size_t)blockIdx.x * BLOCK * VQ_K);
    const int F = BLOCK * (VQ_K / 4);              // 2048
#pragma unroll
    for (int f = tid; f < F; f += BLOCK) {
        int vv = f >> 4;
        int k4 = f & 15;
        hat4[f] = cb4[zsh[vv] * (VQ_K / 4) + k4];
    }
}

extern "C" void kernel_launch(void* const* d_in, const int* in_sizes, int n_in,
                              void* d_out, int out_size, void* d_ws, size_t ws_size,
                              hipStream_t stream) {
    const float* vecs = (const float*)d_in[0];
    const float* codebook = (const float*)d_in[1];
    float* out = (float*)d_out;

    const int nvec = in_sizes[0] / VQ_K;            // 65536
    unsigned char* bimg = (unsigned char*)d_ws;     // 141312 B image

    float* out_hat = out;
    float* out_z = out + (size_t)nvec * VQ_K;
    float* out_loss = out + out_size - 2;

    hipMemsetAsync(out_loss, 0, 2 * sizeof(float), stream);
    vq_prep<<<VQ_S / 4, 256, 0, stream>>>(codebook, bimg);
    vq_mfma<<<nvec / BLOCK, BLOCK, 0, stream>>>(
        vecs, codebook, bimg, out_hat, out_z, out_loss, 1.0f / (float)nvec);
}